// Round 6
// baseline (385.284 us; speedup 1.0000x reference)
//
#include <hip/hip_runtime.h>
#include <math.h>

#define C 64
#define KCOEF 4
#define TN 32          // nodes per kF2 block
#define TROW 321       // padded LDS row (banks: (nl*321+i)%32 distinct over nl)

// ============ kAH: fused [dvec = x . attv] + [dst histogram] ============
// dvec part: 16 nodes/block, 16 lanes per node, float4 per lane
__global__ __launch_bounds__(256) void kAH(const float* __restrict__ x,
        const float* __restrict__ attv, const int* __restrict__ dst,
        float* __restrict__ dvec, int* __restrict__ deg, int N, int E, int NBD) {
    if ((int)blockIdx.x < NBD) {
        int t = threadIdx.x;
        int n = blockIdx.x * 16 + (t >> 4);
        int q = t & 15;
        if (n >= N) return;
        float4 xv = *(const float4*)(x + (size_t)n * C + q * 4);
        float4 av = *(const float4*)(attv + q * 4);
        float p = xv.x * av.x + xv.y * av.y + xv.z * av.z + xv.w * av.w;
        #pragma unroll
        for (int o = 8; o > 0; o >>= 1) p += __shfl_xor(p, o, 16);
        if (q == 0) dvec[n] = p;
    } else {
        int e = ((int)blockIdx.x - NBD) * 256 + (int)threadIdx.x;
        if (e >= E) return;
        atomicAdd(&deg[dst[e]], 1);
    }
}

// ============ scan over deg -> off ============
__global__ __launch_bounds__(256) void kS1(const int* __restrict__ deg,
        int* __restrict__ off, int* __restrict__ bsum, int N) {
    int g = blockIdx.x * 256 + threadIdx.x;
    int lane = threadIdx.x & 63, w = threadIdx.x >> 6;
    int v = (g < N) ? deg[g] : 0;
    int incl = v;
    #pragma unroll
    for (int s = 1; s < 64; s <<= 1) {
        int t = __shfl_up(incl, s);
        if (lane >= s) incl += t;
    }
    __shared__ int wtot[4];
    if (lane == 63) wtot[w] = incl;
    __syncthreads();
    int add = 0;
    for (int ww = 0; ww < w; ++ww) add += wtot[ww];
    int excl = incl - v + add;
    if (g < N) off[g] = excl;
    if (threadIdx.x == 255) bsum[blockIdx.x] = excl + v;
}

__global__ __launch_bounds__(256) void kS2(int* __restrict__ bsum, int NB) {
    int t = threadIdx.x;
    int lane = t & 63, w = t >> 6;
    int v = (t < NB) ? bsum[t] : 0;
    int incl = v;
    #pragma unroll
    for (int s = 1; s < 64; s <<= 1) {
        int tt = __shfl_up(incl, s);
        if (lane >= s) incl += tt;
    }
    __shared__ int wtot[4];
    if (lane == 63) wtot[w] = incl;
    __syncthreads();
    int add = 0;
    for (int ww = 0; ww < w; ++ww) add += wtot[ww];
    if (t < NB) bsum[t] = incl - v + add;
}

__global__ __launch_bounds__(256) void kS3(int* __restrict__ off,
        const int* __restrict__ bsum, int* __restrict__ cur, int N) {
    int g = blockIdx.x * 256 + threadIdx.x;
    if (g >= N) return;
    int o = off[g] + bsum[blockIdx.x];
    off[g] = o;
    cur[g] = o;
}

// ============ kP: CSR scatter, 4 edges/thread for latency overlap ========
__global__ __launch_bounds__(256) void kP(const int* __restrict__ src,
        const int* __restrict__ dst, const float* __restrict__ ea,
        const float* __restrict__ dvec, int* __restrict__ cur,
        float* __restrict__ rawS, int* __restrict__ eidS, int E) {
    int base = (blockIdx.x * 256 + threadIdx.x) * 4;
    float r[4]; int d[4]; int ok[4];
    #pragma unroll
    for (int j = 0; j < 4; ++j) {
        int e = base + j;
        ok[j] = (e < E);
        if (ok[j]) {
            float4 a = ((const float4*)ea)[e];
            float mean = (a.x + a.y + a.z + a.w) * 0.25f;
            r[j] = mean * dvec[src[e]];
            d[j] = dst[e];
        }
    }
    int p[4];
    #pragma unroll
    for (int j = 0; j < 4; ++j) if (ok[j]) p[j] = atomicAdd(&cur[d[j]], 1);
    #pragma unroll
    for (int j = 0; j < 4; ++j) if (ok[j]) { rawS[p[j]] = r[j]; eidS[p[j]] = base + j; }
}

// ============ kE2: per-node softmax stats + batched x-space aggregation ====
__global__ __launch_bounds__(256) void kE2(const float* __restrict__ x,
        const float* __restrict__ ea, const int* __restrict__ src,
        const int* __restrict__ off,
        const int* degp, float* invOut,          // aliased (deg buffer)
        const float* __restrict__ rawS, const int* __restrict__ eidS,
        float* mOut,                              // aliased (cur buffer)
        float* __restrict__ agg, int N) {
    __shared__ float sb[4][64][8];
    int wv = __builtin_amdgcn_readfirstlane(threadIdx.x >> 6);
    int lane = threadIdx.x & 63;
    int n = blockIdx.x * 4 + wv;
    if (n >= N) return;
    int s0 = off[n];
    int dg = degp[n];
    size_t ab = (size_t)n * (KCOEF * C) + lane;
    if (dg == 0) {
        agg[ab] = 0.f; agg[ab + 64] = 0.f; agg[ab + 128] = 0.f; agg[ab + 192] = 0.f;
        if (lane == 0) { mOut[n] = 0.f; invOut[n] = 1.f; }
        return;
    }
    float m = -INFINITY;
    for (int b = 0; b < dg; b += 64) {
        int i = b + lane;
        if (i < dg) m = fmaxf(m, rawS[s0 + i]);
    }
    #pragma unroll
    for (int o = 32; o > 0; o >>= 1) m = fmaxf(m, __shfl_xor(m, o));
    float ss = 0.f;
    for (int b = 0; b < dg; b += 64) {
        int i = b + lane;
        if (i < dg) ss += expf(rawS[s0 + i] - m);
    }
    #pragma unroll
    for (int o = 32; o > 0; o >>= 1) ss += __shfl_xor(ss, o);
    float inv = 1.f / (ss + 1e-16f);
    if (lane == 0) { mOut[n] = m; invOut[n] = inv; }
    float a0 = 0.f, a1 = 0.f, a2 = 0.f, a3 = 0.f;
    const char* xl = (const char*)x + (size_t)lane * 4;
    for (int b = 0; b < dg; b += 64) {
        int i = b + lane;
        int blen = min(64, dg - b);
        if (i < dg) {
            int e0 = eidS[s0 + i];
            int sN = src[e0];
            float4 c4 = *(const float4*)(ea + (size_t)e0 * 4);
            float w = 1.f + expf(rawS[s0 + i] - m) * inv;
            sb[wv][lane][0] = c4.x * w;
            sb[wv][lane][1] = c4.y * w;
            sb[wv][lane][2] = c4.z * w;
            sb[wv][lane][3] = c4.w * w;
            ((int*)&sb[wv][lane][0])[4] = sN * (C * 4);
        }
        #pragma unroll 4
        for (int j = 0; j < blen; ++j) {
            float4 e4 = *(const float4*)&sb[wv][j][0];
            int ob = ((const int*)&sb[wv][j][0])[4];
            float xr = *(const float*)(xl + ob);
            a0 = fmaf(e4.x, xr, a0);
            a1 = fmaf(e4.y, xr, a1);
            a2 = fmaf(e4.z, xr, a2);
            a3 = fmaf(e4.w, xr, a3);
        }
    }
    agg[ab] = a0; agg[ab + 64] = a1; agg[ab + 128] = a2; agg[ab + 192] = a3;
}

// ============ kF2: out = bias + [agg | x] @ Wflat[320][64], LDS-tiled ======
//              + fused coalesced out_att edge pass
__global__ __launch_bounds__(256) void kF2(const float* __restrict__ agg,
        const float* __restrict__ x, const float* __restrict__ W,
        const float* __restrict__ bias, float* __restrict__ out_node,
        const int* __restrict__ src, const int* __restrict__ dst,
        const float* __restrict__ ea, const float* __restrict__ dvec,
        const float* __restrict__ mA, const float* __restrict__ invA,
        float* __restrict__ out_att, int N, int E, int NBF) {
    if ((int)blockIdx.x < NBF) {
        __shared__ float T[TN * TROW];
        int tid = threadIdx.x;
        int nbase = blockIdx.x * TN;
        // stage [agg | x] rows (clamped) into padded LDS tile
        for (int idx = tid; idx < TN * 320; idx += 256) {
            int row = idx / 320;
            int col = idx - row * 320;
            int n = nbase + row; if (n >= N) n = N - 1;
            float v = (col < 256) ? agg[(size_t)n * 256 + col]
                                  : x[(size_t)n * C + (col - 256)];
            T[row * TROW + col] = v;
        }
        __syncthreads();
        int nl = tid & 31;           // node lane
        int c0 = (tid >> 5) * 8;     // 8-channel group
        const float* Tr = T + nl * TROW;
        float acc0, acc1, acc2, acc3, acc4, acc5, acc6, acc7;
        {
            float4 bA = *(const float4*)(bias + c0);
            float4 bB = *(const float4*)(bias + c0 + 4);
            acc0 = bA.x; acc1 = bA.y; acc2 = bA.z; acc3 = bA.w;
            acc4 = bB.x; acc5 = bB.y; acc6 = bB.z; acc7 = bB.w;
        }
        #pragma unroll 4
        for (int i = 0; i < 320; ++i) {
            float tv = Tr[i];
            float4 wA = *(const float4*)(W + (size_t)i * 64 + c0);
            float4 wB = *(const float4*)(W + (size_t)i * 64 + c0 + 4);
            acc0 = fmaf(tv, wA.x, acc0);
            acc1 = fmaf(tv, wA.y, acc1);
            acc2 = fmaf(tv, wA.z, acc2);
            acc3 = fmaf(tv, wA.w, acc3);
            acc4 = fmaf(tv, wB.x, acc4);
            acc5 = fmaf(tv, wB.y, acc5);
            acc6 = fmaf(tv, wB.z, acc6);
            acc7 = fmaf(tv, wB.w, acc7);
        }
        int n = nbase + nl;
        if (n < N) {
            float4 oA = { acc0, acc1, acc2, acc3 };
            float4 oB = { acc4, acc5, acc6, acc7 };
            *(float4*)(out_node + (size_t)n * C + c0) = oA;
            *(float4*)(out_node + (size_t)n * C + c0 + 4) = oB;
        }
    } else {
        int e = ((int)blockIdx.x - NBF) * 256 + (int)threadIdx.x;
        if (e >= E) return;
        float4 a = ((const float4*)ea)[e];
        float mean = (a.x + a.y + a.z + a.w) * 0.25f;
        float r = mean * dvec[src[e]];          // bitwise-identical to kP's logit
        int d = dst[e];
        out_att[e] = expf(r - mA[d]) * invA[d];
    }
}

extern "C" void kernel_launch(void* const* d_in, const int* in_sizes, int n_in,
                              void* d_out, int out_size, void* d_ws, size_t ws_size,
                              hipStream_t stream) {
    const float* x    = (const float*)d_in[0];
    const float* ea   = (const float*)d_in[1];
    const float* W    = (const float*)d_in[2];
    const float* bias = (const float*)d_in[3];
    const float* attv = (const float*)d_in[4];
    const int*   ei   = (const int*)d_in[5];

    int N = in_sizes[0] / C;
    int E = in_sizes[5] / 2;
    const int* src = ei;
    const int* dst = ei + E;

    float* out_node = (float*)d_out;
    float* out_att  = (float*)d_out + (size_t)N * C;

    char* ws = (char*)d_ws;
    float* agg  = (float*)ws; ws += (size_t)N * KCOEF * C * sizeof(float);
    float* rawS = (float*)ws; ws += (size_t)E * sizeof(float);
    int*   eidS = (int*)ws;   ws += (size_t)E * sizeof(int);
    float* dvec = (float*)ws; ws += (size_t)N * sizeof(float);
    int*   deg  = (int*)ws;   ws += (size_t)N * sizeof(int);
    int*   off  = (int*)ws;   ws += (size_t)N * sizeof(int);
    int*   cur  = (int*)ws;   ws += (size_t)N * sizeof(int);
    int*   bsum = (int*)ws;   ws += 1024;

    // overlays (dead-after-use buffers reused for softmax stats)
    float* mA   = (float*)cur;   // cur dead after kP
    float* invA = (float*)deg;   // deg dead after kE2 reads it

    int NB  = (N + 255) / 256;       // scan blocks (196 <= 256)
    int NBD = (N + 15) / 16;         // dvec blocks
    int NBH = (E + 255) / 256;       // histogram blocks
    int NBF = (N + TN - 1) / TN;     // kF2 node blocks
    int NBT = (E + 255) / 256;       // out_att blocks

    hipMemsetAsync(deg, 0, (size_t)N * sizeof(int), stream);
    kAH <<<NBD + NBH, 256, 0, stream>>>(x, attv, dst, dvec, deg, N, E, NBD);
    kS1 <<<NB, 256, 0, stream>>>(deg, off, bsum, N);
    kS2 <<<1, 256, 0, stream>>>(bsum, NB);
    kS3 <<<NB, 256, 0, stream>>>(off, bsum, cur, N);
    kP  <<<(E + 1023) / 1024, 256, 0, stream>>>(src, dst, ea, dvec, cur, rawS, eidS, E);
    kE2 <<<(N + 3) / 4, 256, 0, stream>>>(x, ea, src, off, deg, invA, rawS, eidS, mA, agg, N);
    kF2 <<<NBF + NBT, 256, 0, stream>>>(agg, x, W, bias, out_node, src, dst, ea, dvec, mA, invA, out_att, N, E, NBF);
}

// Round 7
// 298.632 us; speedup vs baseline: 1.2902x; 1.2902x over previous
//
#include <hip/hip_runtime.h>
#include <math.h>

#define C 64
#define KCOEF 4
#define FN 128         // nodes per kF3 block
#define FK 64          // k-chunk
#define APAD 65        // As row pad (floats)

// ============ kAH: fused [dvec = x . attv] + [dst histogram] ============
__global__ __launch_bounds__(256) void kAH(const float* __restrict__ x,
        const float* __restrict__ attv, const int* __restrict__ dst,
        float* __restrict__ dvec, int* __restrict__ deg, int N, int E, int NBD) {
    if ((int)blockIdx.x < NBD) {
        int t = threadIdx.x;
        int n = blockIdx.x * 16 + (t >> 4);
        int q = t & 15;
        if (n >= N) return;
        float4 xv = *(const float4*)(x + (size_t)n * C + q * 4);
        float4 av = *(const float4*)(attv + q * 4);
        float p = xv.x * av.x + xv.y * av.y + xv.z * av.z + xv.w * av.w;
        #pragma unroll
        for (int o = 8; o > 0; o >>= 1) p += __shfl_xor(p, o, 16);
        if (q == 0) dvec[n] = p;
    } else {
        int e = ((int)blockIdx.x - NBD) * 256 + (int)threadIdx.x;
        if (e >= E) return;
        atomicAdd(&deg[dst[e]], 1);
    }
}

// ============ scan over deg -> off ============
__global__ __launch_bounds__(256) void kS1(const int* __restrict__ deg,
        int* __restrict__ off, int* __restrict__ bsum, int N) {
    int g = blockIdx.x * 256 + threadIdx.x;
    int lane = threadIdx.x & 63, w = threadIdx.x >> 6;
    int v = (g < N) ? deg[g] : 0;
    int incl = v;
    #pragma unroll
    for (int s = 1; s < 64; s <<= 1) {
        int t = __shfl_up(incl, s);
        if (lane >= s) incl += t;
    }
    __shared__ int wtot[4];
    if (lane == 63) wtot[w] = incl;
    __syncthreads();
    int add = 0;
    for (int ww = 0; ww < w; ++ww) add += wtot[ww];
    int excl = incl - v + add;
    if (g < N) off[g] = excl;
    if (threadIdx.x == 255) bsum[blockIdx.x] = excl + v;
}

__global__ __launch_bounds__(256) void kS2(int* __restrict__ bsum, int NB) {
    int t = threadIdx.x;
    int lane = t & 63, w = t >> 6;
    int v = (t < NB) ? bsum[t] : 0;
    int incl = v;
    #pragma unroll
    for (int s = 1; s < 64; s <<= 1) {
        int tt = __shfl_up(incl, s);
        if (lane >= s) incl += tt;
    }
    __shared__ int wtot[4];
    if (lane == 63) wtot[w] = incl;
    __syncthreads();
    int add = 0;
    for (int ww = 0; ww < w; ++ww) add += wtot[ww];
    if (t < NB) bsum[t] = incl - v + add;
}

__global__ __launch_bounds__(256) void kS3(int* __restrict__ off,
        const int* __restrict__ bsum, int* __restrict__ cur, int N) {
    int g = blockIdx.x * 256 + threadIdx.x;
    if (g >= N) return;
    int o = off[g] + bsum[blockIdx.x];
    off[g] = o;
    cur[g] = o;
}

// ============ kP: CSR scatter, 4 edges/thread ============
__global__ __launch_bounds__(256) void kP(const int* __restrict__ src,
        const int* __restrict__ dst, const float* __restrict__ ea,
        const float* __restrict__ dvec, int* __restrict__ cur,
        float* __restrict__ rawS, int* __restrict__ eidS, int E) {
    int base = (blockIdx.x * 256 + threadIdx.x) * 4;
    float r[4]; int d[4]; int ok[4];
    #pragma unroll
    for (int j = 0; j < 4; ++j) {
        int e = base + j;
        ok[j] = (e < E);
        if (ok[j]) {
            float4 a = ((const float4*)ea)[e];
            float mean = (a.x + a.y + a.z + a.w) * 0.25f;
            r[j] = mean * dvec[src[e]];
            d[j] = dst[e];
        }
    }
    int p[4];
    #pragma unroll
    for (int j = 0; j < 4; ++j) if (ok[j]) p[j] = atomicAdd(&cur[d[j]], 1);
    #pragma unroll
    for (int j = 0; j < 4; ++j) if (ok[j]) { rawS[p[j]] = r[j]; eidS[p[j]] = base + j; }
}

// ============ kE2: per-node softmax stats + batched x-space aggregation ====
__global__ __launch_bounds__(256) void kE2(const float* __restrict__ x,
        const float* __restrict__ ea, const int* __restrict__ src,
        const int* __restrict__ off,
        const int* degp, float* invOut,          // aliased (deg buffer)
        const float* __restrict__ rawS, const int* __restrict__ eidS,
        float* mOut,                              // aliased (cur buffer)
        float* __restrict__ agg, int N) {
    __shared__ float sb[4][64][8];
    int wv = __builtin_amdgcn_readfirstlane(threadIdx.x >> 6);
    int lane = threadIdx.x & 63;
    int n = blockIdx.x * 4 + wv;
    if (n >= N) return;
    int s0 = off[n];
    int dg = degp[n];
    size_t ab = (size_t)n * (KCOEF * C) + lane;
    if (dg == 0) {
        agg[ab] = 0.f; agg[ab + 64] = 0.f; agg[ab + 128] = 0.f; agg[ab + 192] = 0.f;
        if (lane == 0) { mOut[n] = 0.f; invOut[n] = 1.f; }
        return;
    }
    float m = -INFINITY;
    for (int b = 0; b < dg; b += 64) {
        int i = b + lane;
        if (i < dg) m = fmaxf(m, rawS[s0 + i]);
    }
    #pragma unroll
    for (int o = 32; o > 0; o >>= 1) m = fmaxf(m, __shfl_xor(m, o));
    float ss = 0.f;
    for (int b = 0; b < dg; b += 64) {
        int i = b + lane;
        if (i < dg) ss += expf(rawS[s0 + i] - m);
    }
    #pragma unroll
    for (int o = 32; o > 0; o >>= 1) ss += __shfl_xor(ss, o);
    float inv = 1.f / (ss + 1e-16f);
    if (lane == 0) { mOut[n] = m; invOut[n] = inv; }
    float a0 = 0.f, a1 = 0.f, a2 = 0.f, a3 = 0.f;
    const char* xl = (const char*)x + (size_t)lane * 4;
    for (int b = 0; b < dg; b += 64) {
        int i = b + lane;
        int blen = min(64, dg - b);
        if (i < dg) {
            int e0 = eidS[s0 + i];
            int sN = src[e0];
            float4 c4 = *(const float4*)(ea + (size_t)e0 * 4);
            float w = 1.f + expf(rawS[s0 + i] - m) * inv;
            sb[wv][lane][0] = c4.x * w;
            sb[wv][lane][1] = c4.y * w;
            sb[wv][lane][2] = c4.z * w;
            sb[wv][lane][3] = c4.w * w;
            ((int*)&sb[wv][lane][0])[4] = sN * (C * 4);
        }
        #pragma unroll 4
        for (int j = 0; j < blen; ++j) {
            float4 e4 = *(const float4*)&sb[wv][j][0];
            int ob = ((const int*)&sb[wv][j][0])[4];
            float xr = *(const float*)(xl + ob);
            a0 = fmaf(e4.x, xr, a0);
            a1 = fmaf(e4.y, xr, a1);
            a2 = fmaf(e4.z, xr, a2);
            a3 = fmaf(e4.w, xr, a3);
        }
    }
    agg[ab] = a0; agg[ab + 64] = a1; agg[ab + 128] = a2; agg[ab + 192] = a3;
}

// ============ kF3: out = bias + [agg | x] @ Wflat[320][64] ================
// LDS double-staged GEMM: As[128][FK] (padded) + Ws[FK][64] per k-chunk.
// thread = (node-quad ng, channel-octet cg): 4x8 register tile, 32 fma/k.
__global__ __launch_bounds__(256) void kF3(const float* __restrict__ agg,
        const float* __restrict__ x, const float* __restrict__ W,
        const float* __restrict__ bias, float* __restrict__ out_node, int N) {
    __shared__ float As[FN][APAD];
    __shared__ float Ws[FK][C];
    int tid = threadIdx.x;
    int nbase = blockIdx.x * FN;
    int ng = tid >> 3;          // 0..31
    int cg = tid & 7;           // 0..7
    float4 acc0[4], acc1[4];
    #pragma unroll
    for (int j = 0; j < 4; ++j) { acc0[j] = {0,0,0,0}; acc1[j] = {0,0,0,0}; }

    int srow_q = tid & 15;      // staging col-quad
    int srow_b = tid >> 4;      // staging row within pass (0..15)

    for (int k0 = 0; k0 < 320; k0 += FK) {
        // stage A chunk: [128 nodes][64 k], transposed-free padded rows
        #pragma unroll
        for (int pass = 0; pass < 8; ++pass) {
            int row = pass * 16 + srow_b;
            int n = nbase + row; if (n >= N) n = N - 1;
            float4 v;
            if (k0 < 256) v = *(const float4*)(agg + (size_t)n * 256 + k0 + srow_q * 4);
            else          v = *(const float4*)(x   + (size_t)n * C   + srow_q * 4);
            As[row][srow_q * 4 + 0] = v.x;
            As[row][srow_q * 4 + 1] = v.y;
            As[row][srow_q * 4 + 2] = v.z;
            As[row][srow_q * 4 + 3] = v.w;
        }
        // stage W chunk: rows k0..k0+63, linear copy
        #pragma unroll
        for (int p = 0; p < 4; ++p) {
            int idx = tid + p * 256;            // float4 index in [0,1024)
            ((float4*)Ws)[idx] = ((const float4*)(W + (size_t)k0 * C))[idx];
        }
        __syncthreads();
        #pragma unroll 2
        for (int i = 0; i < FK; ++i) {
            float a0 = As[ng * 4 + 0][i];
            float a1 = As[ng * 4 + 1][i];
            float a2 = As[ng * 4 + 2][i];
            float a3 = As[ng * 4 + 3][i];
            float4 w0 = *(const float4*)&Ws[i][cg * 8];
            float4 w1 = *(const float4*)&Ws[i][cg * 8 + 4];
            acc0[0].x = fmaf(a0, w0.x, acc0[0].x); acc0[0].y = fmaf(a0, w0.y, acc0[0].y);
            acc0[0].z = fmaf(a0, w0.z, acc0[0].z); acc0[0].w = fmaf(a0, w0.w, acc0[0].w);
            acc1[0].x = fmaf(a0, w1.x, acc1[0].x); acc1[0].y = fmaf(a0, w1.y, acc1[0].y);
            acc1[0].z = fmaf(a0, w1.z, acc1[0].z); acc1[0].w = fmaf(a0, w1.w, acc1[0].w);
            acc0[1].x = fmaf(a1, w0.x, acc0[1].x); acc0[1].y = fmaf(a1, w0.y, acc0[1].y);
            acc0[1].z = fmaf(a1, w0.z, acc0[1].z); acc0[1].w = fmaf(a1, w0.w, acc0[1].w);
            acc1[1].x = fmaf(a1, w1.x, acc1[1].x); acc1[1].y = fmaf(a1, w1.y, acc1[1].y);
            acc1[1].z = fmaf(a1, w1.z, acc1[1].z); acc1[1].w = fmaf(a1, w1.w, acc1[1].w);
            acc0[2].x = fmaf(a2, w0.x, acc0[2].x); acc0[2].y = fmaf(a2, w0.y, acc0[2].y);
            acc0[2].z = fmaf(a2, w0.z, acc0[2].z); acc0[2].w = fmaf(a2, w0.w, acc0[2].w);
            acc1[2].x = fmaf(a2, w1.x, acc1[2].x); acc1[2].y = fmaf(a2, w1.y, acc1[2].y);
            acc1[2].z = fmaf(a2, w1.z, acc1[2].z); acc1[2].w = fmaf(a2, w1.w, acc1[2].w);
            acc0[3].x = fmaf(a3, w0.x, acc0[3].x); acc0[3].y = fmaf(a3, w0.y, acc0[3].y);
            acc0[3].z = fmaf(a3, w0.z, acc0[3].z); acc0[3].w = fmaf(a3, w0.w, acc0[3].w);
            acc1[3].x = fmaf(a3, w1.x, acc1[3].x); acc1[3].y = fmaf(a3, w1.y, acc1[3].y);
            acc1[3].z = fmaf(a3, w1.z, acc1[3].z); acc1[3].w = fmaf(a3, w1.w, acc1[3].w);
        }
        __syncthreads();
    }
    float4 bA = *(const float4*)(bias + cg * 8);
    float4 bB = *(const float4*)(bias + cg * 8 + 4);
    #pragma unroll
    for (int j = 0; j < 4; ++j) {
        int n = nbase + ng * 4 + j;
        if (n < N) {
            float4 oA = { acc0[j].x + bA.x, acc0[j].y + bA.y, acc0[j].z + bA.z, acc0[j].w + bA.w };
            float4 oB = { acc1[j].x + bB.x, acc1[j].y + bB.y, acc1[j].z + bB.z, acc1[j].w + bB.w };
            *(float4*)(out_node + (size_t)n * C + cg * 8)     = oA;
            *(float4*)(out_node + (size_t)n * C + cg * 8 + 4) = oB;
        }
    }
}

// ============ kT: coalesced out_att (recompute bitwise-identical logit) ====
__global__ __launch_bounds__(256) void kT(const int* __restrict__ src,
        const int* __restrict__ dst, const float* __restrict__ ea,
        const float* __restrict__ dvec, const float* __restrict__ mA,
        const float* __restrict__ invA, float* __restrict__ out_att, int E) {
    int e = blockIdx.x * 256 + threadIdx.x;
    if (e >= E) return;
    float4 a = ((const float4*)ea)[e];
    float mean = (a.x + a.y + a.z + a.w) * 0.25f;
    float r = mean * dvec[src[e]];
    int d = dst[e];
    out_att[e] = expf(r - mA[d]) * invA[d];
}

extern "C" void kernel_launch(void* const* d_in, const int* in_sizes, int n_in,
                              void* d_out, int out_size, void* d_ws, size_t ws_size,
                              hipStream_t stream) {
    const float* x    = (const float*)d_in[0];
    const float* ea   = (const float*)d_in[1];
    const float* W    = (const float*)d_in[2];
    const float* bias = (const float*)d_in[3];
    const float* attv = (const float*)d_in[4];
    const int*   ei   = (const int*)d_in[5];

    int N = in_sizes[0] / C;
    int E = in_sizes[5] / 2;
    const int* src = ei;
    const int* dst = ei + E;

    float* out_node = (float*)d_out;
    float* out_att  = (float*)d_out + (size_t)N * C;

    char* ws = (char*)d_ws;
    float* agg  = (float*)ws; ws += (size_t)N * KCOEF * C * sizeof(float);
    float* rawS = (float*)ws; ws += (size_t)E * sizeof(float);
    int*   eidS = (int*)ws;   ws += (size_t)E * sizeof(int);
    float* dvec = (float*)ws; ws += (size_t)N * sizeof(float);
    int*   deg  = (int*)ws;   ws += (size_t)N * sizeof(int);
    int*   off  = (int*)ws;   ws += (size_t)N * sizeof(int);
    int*   cur  = (int*)ws;   ws += (size_t)N * sizeof(int);
    int*   bsum = (int*)ws;   ws += 1024;

    // overlays (dead-after-use buffers reused for softmax stats)
    float* mA   = (float*)cur;   // cur dead after kP
    float* invA = (float*)deg;   // deg dead after kE2 reads it

    int NB  = (N + 255) / 256;       // scan blocks (196 <= 256)
    int NBD = (N + 15) / 16;         // dvec blocks
    int NBH = (E + 255) / 256;       // histogram blocks
    int NBF = (N + FN - 1) / FN;     // kF3 node blocks

    hipMemsetAsync(deg, 0, (size_t)N * sizeof(int), stream);
    kAH <<<NBD + NBH, 256, 0, stream>>>(x, attv, dst, dvec, deg, N, E, NBD);
    kS1 <<<NB, 256, 0, stream>>>(deg, off, bsum, N);
    kS2 <<<1, 256, 0, stream>>>(bsum, NB);
    kS3 <<<NB, 256, 0, stream>>>(off, bsum, cur, N);
    kP  <<<(E + 1023) / 1024, 256, 0, stream>>>(src, dst, ea, dvec, cur, rawS, eidS, E);
    kE2 <<<(N + 3) / 4, 256, 0, stream>>>(x, ea, src, off, deg, invA, rawS, eidS, mA, agg, N);
    kF3 <<<NBF, 256, 0, stream>>>(agg, x, W, bias, out_node, N);
    kT  <<<(E + 255) / 256, 256, 0, stream>>>(src, dst, ea, dvec, mA, invA, out_att, E);
}

// Round 8
// 275.201 us; speedup vs baseline: 1.4000x; 1.0851x over previous
//
#include <hip/hip_runtime.h>
#include <math.h>

#define C 64
#define KCOEF 4
#define FN 128         // nodes per kF3 block
#define FK 64          // k-chunk
#define APAD 65        // As row pad (floats)

// ============ kAH: fused [dvec = x . attv] + [dst histogram] ============
__global__ __launch_bounds__(256) void kAH(const float* __restrict__ x,
        const float* __restrict__ attv, const int* __restrict__ dst,
        float* __restrict__ dvec, int* __restrict__ deg, int N, int E, int NBD) {
    if ((int)blockIdx.x < NBD) {
        int t = threadIdx.x;
        int n = blockIdx.x * 16 + (t >> 4);
        int q = t & 15;
        if (n >= N) return;
        float4 xv = *(const float4*)(x + (size_t)n * C + q * 4);
        float4 av = *(const float4*)(attv + q * 4);
        float p = xv.x * av.x + xv.y * av.y + xv.z * av.z + xv.w * av.w;
        #pragma unroll
        for (int o = 8; o > 0; o >>= 1) p += __shfl_xor(p, o, 16);
        if (q == 0) dvec[n] = p;
    } else {
        int e = ((int)blockIdx.x - NBD) * 256 + (int)threadIdx.x;
        if (e >= E) return;
        atomicAdd(&deg[dst[e]], 1);
    }
}

// ============ scan over deg -> off ============
__global__ __launch_bounds__(256) void kS1(const int* __restrict__ deg,
        int* __restrict__ off, int* __restrict__ bsum, int N) {
    int g = blockIdx.x * 256 + threadIdx.x;
    int lane = threadIdx.x & 63, w = threadIdx.x >> 6;
    int v = (g < N) ? deg[g] : 0;
    int incl = v;
    #pragma unroll
    for (int s = 1; s < 64; s <<= 1) {
        int t = __shfl_up(incl, s);
        if (lane >= s) incl += t;
    }
    __shared__ int wtot[4];
    if (lane == 63) wtot[w] = incl;
    __syncthreads();
    int add = 0;
    for (int ww = 0; ww < w; ++ww) add += wtot[ww];
    int excl = incl - v + add;
    if (g < N) off[g] = excl;
    if (threadIdx.x == 255) bsum[blockIdx.x] = excl + v;
}

__global__ __launch_bounds__(256) void kS2(int* __restrict__ bsum, int NB) {
    int t = threadIdx.x;
    int lane = t & 63, w = t >> 6;
    int v = (t < NB) ? bsum[t] : 0;
    int incl = v;
    #pragma unroll
    for (int s = 1; s < 64; s <<= 1) {
        int tt = __shfl_up(incl, s);
        if (lane >= s) incl += tt;
    }
    __shared__ int wtot[4];
    if (lane == 63) wtot[w] = incl;
    __syncthreads();
    int add = 0;
    for (int ww = 0; ww < w; ++ww) add += wtot[ww];
    if (t < NB) bsum[t] = incl - v + add;
}

__global__ __launch_bounds__(256) void kS3(int* __restrict__ off,
        const int* __restrict__ bsum, int* __restrict__ cur, int N) {
    int g = blockIdx.x * 256 + threadIdx.x;
    if (g >= N) return;
    int o = off[g] + bsum[blockIdx.x];
    off[g] = o;
    cur[g] = o;
}

// ============ kP: CSR scatter of 32-B payload {r, srcoff, ea4, pad2} =======
__global__ __launch_bounds__(256) void kP(const int* __restrict__ src,
        const int* __restrict__ dst, const float* __restrict__ ea,
        const float* __restrict__ dvec, int* __restrict__ cur,
        float4* __restrict__ pay, int E) {
    int base = (blockIdx.x * 256 + threadIdx.x) * 4;
    float4 q0[4], q1[4]; int d[4]; int ok[4];
    #pragma unroll
    for (int j = 0; j < 4; ++j) {
        int e = base + j;
        ok[j] = (e < E);
        if (ok[j]) {
            float4 a = ((const float4*)ea)[e];
            float mean = (a.x + a.y + a.z + a.w) * 0.25f;
            int sN = src[e];
            float r = mean * dvec[sN];
            d[j] = dst[e];
            q0[j].x = r;
            q0[j].y = __int_as_float(sN * (C * 4));   // x-row byte offset (raw bits)
            q0[j].z = a.x; q0[j].w = a.y;
            q1[j].x = a.z; q1[j].y = a.w; q1[j].z = 0.f; q1[j].w = 0.f;
        }
    }
    int p[4];
    #pragma unroll
    for (int j = 0; j < 4; ++j) if (ok[j]) p[j] = atomicAdd(&cur[d[j]], 1);
    #pragma unroll
    for (int j = 0; j < 4; ++j) if (ok[j]) {
        pay[(size_t)p[j] * 2]     = q0[j];
        pay[(size_t)p[j] * 2 + 1] = q1[j];
    }
}

// ============ kE3: single-pass online-softmax + dual aggregation ==========
// one wave per dst node; lane = input channel. Payload read coalesced.
__global__ __launch_bounds__(256) void kE3(const float* __restrict__ x,
        const float4* __restrict__ pay, const int* __restrict__ off,
        const int* degp, float* invOut,          // aliased (deg buffer)
        float* mOut,                              // aliased (cur buffer)
        float* __restrict__ agg, int N, int E) {
    __shared__ float sb[4][64][8];
    int wv = __builtin_amdgcn_readfirstlane(threadIdx.x >> 6);
    int lane = threadIdx.x & 63;
    int n = blockIdx.x * 4 + wv;
    if (n >= N) return;
    int s0 = off[n];
    int dg = degp[n];
    size_t ab = (size_t)n * (KCOEF * C) + lane;
    if (dg == 0) {
        agg[ab] = 0.f; agg[ab + 64] = 0.f; agg[ab + 128] = 0.f; agg[ab + 192] = 0.f;
        if (lane == 0) { mOut[n] = 0.f; invOut[n] = 1.f; }
        return;
    }
    float m_run = -INFINITY, ss = 0.f;
    float sA0 = 0.f, sA1 = 0.f, sA2 = 0.f, sA3 = 0.f;
    float aA0 = 0.f, aA1 = 0.f, aA2 = 0.f, aA3 = 0.f;
    const char* xl = (const char*)x + (size_t)lane * 4;
    for (int b = 0; b < dg; b += 64) {
        int i = b + lane;
        int idx = s0 + (i < dg ? i : dg - 1);
        float4 p0 = pay[(size_t)idx * 2];
        float4 p1 = pay[(size_t)idx * 2 + 1];
        float r = (i < dg) ? p0.x : -INFINITY;
        // wave-uniform batch max
        float bm = r;
        #pragma unroll
        for (int o = 32; o > 0; o >>= 1) bm = fmaxf(bm, __shfl_xor(bm, o));
        if (bm > m_run) {
            float sc = expf(m_run - bm);     // 0 on first batch (exp(-inf))
            ss *= sc;
            aA0 *= sc; aA1 *= sc; aA2 *= sc; aA3 *= sc;
            m_run = bm;
        }
        float w = expf(r - m_run);           // 0 for masked lanes
        float bs = w;
        #pragma unroll
        for (int o = 32; o > 0; o >>= 1) bs += __shfl_xor(bs, o);
        ss += bs;
        // stash {ea4, w, xoff} in wave-private LDS (wave-synchronous)
        sb[wv][lane][0] = p0.z;
        sb[wv][lane][1] = p0.w;
        sb[wv][lane][2] = p1.x;
        sb[wv][lane][3] = p1.y;
        sb[wv][lane][4] = w;
        ((int*)&sb[wv][lane][0])[5] = __float_as_int(p0.y);  // xoff bits
        int blen = min(64, dg - b);
        #pragma unroll 4
        for (int j = 0; j < blen; ++j) {
            float4 e4 = *(const float4*)&sb[wv][j][0];
            float wj = sb[wv][j][4];
            int ob = ((const int*)&sb[wv][j][0])[5];
            float xr = *(const float*)(xl + ob);
            float t0 = e4.x * xr, t1 = e4.y * xr, t2 = e4.z * xr, t3 = e4.w * xr;
            sA0 += t0; sA1 += t1; sA2 += t2; sA3 += t3;
            aA0 = fmaf(wj, t0, aA0); aA1 = fmaf(wj, t1, aA1);
            aA2 = fmaf(wj, t2, aA2); aA3 = fmaf(wj, t3, aA3);
        }
    }
    float inv = 1.f / (ss + 1e-16f);
    if (lane == 0) { mOut[n] = m_run; invOut[n] = inv; }
    agg[ab]       = sA0 + inv * aA0;
    agg[ab + 64]  = sA1 + inv * aA1;
    agg[ab + 128] = sA2 + inv * aA2;
    agg[ab + 192] = sA3 + inv * aA3;
}

// ============ kF3: out = bias + [agg | x] @ Wflat[320][64] ================
__global__ __launch_bounds__(256) void kF3(const float* __restrict__ agg,
        const float* __restrict__ x, const float* __restrict__ W,
        const float* __restrict__ bias, float* __restrict__ out_node, int N) {
    __shared__ float As[FN][APAD];
    __shared__ float Ws[FK][C];
    int tid = threadIdx.x;
    int nbase = blockIdx.x * FN;
    int ng = tid >> 3;          // 0..31
    int cg = tid & 7;           // 0..7
    float4 acc0[4], acc1[4];
    #pragma unroll
    for (int j = 0; j < 4; ++j) { acc0[j] = {0,0,0,0}; acc1[j] = {0,0,0,0}; }

    int srow_q = tid & 15;      // staging col-quad
    int srow_b = tid >> 4;      // staging row within pass (0..15)

    for (int k0 = 0; k0 < 320; k0 += FK) {
        #pragma unroll
        for (int pass = 0; pass < 8; ++pass) {
            int row = pass * 16 + srow_b;
            int n = nbase + row; if (n >= N) n = N - 1;
            float4 v;
            if (k0 < 256) v = *(const float4*)(agg + (size_t)n * 256 + k0 + srow_q * 4);
            else          v = *(const float4*)(x   + (size_t)n * C   + srow_q * 4);
            As[row][srow_q * 4 + 0] = v.x;
            As[row][srow_q * 4 + 1] = v.y;
            As[row][srow_q * 4 + 2] = v.z;
            As[row][srow_q * 4 + 3] = v.w;
        }
        #pragma unroll
        for (int p = 0; p < 4; ++p) {
            int idx = tid + p * 256;
            ((float4*)Ws)[idx] = ((const float4*)(W + (size_t)k0 * C))[idx];
        }
        __syncthreads();
        #pragma unroll 2
        for (int i = 0; i < FK; ++i) {
            float a0 = As[ng * 4 + 0][i];
            float a1 = As[ng * 4 + 1][i];
            float a2 = As[ng * 4 + 2][i];
            float a3 = As[ng * 4 + 3][i];
            float4 w0 = *(const float4*)&Ws[i][cg * 8];
            float4 w1 = *(const float4*)&Ws[i][cg * 8 + 4];
            acc0[0].x = fmaf(a0, w0.x, acc0[0].x); acc0[0].y = fmaf(a0, w0.y, acc0[0].y);
            acc0[0].z = fmaf(a0, w0.z, acc0[0].z); acc0[0].w = fmaf(a0, w0.w, acc0[0].w);
            acc1[0].x = fmaf(a0, w1.x, acc1[0].x); acc1[0].y = fmaf(a0, w1.y, acc1[0].y);
            acc1[0].z = fmaf(a0, w1.z, acc1[0].z); acc1[0].w = fmaf(a0, w1.w, acc1[0].w);
            acc0[1].x = fmaf(a1, w0.x, acc0[1].x); acc0[1].y = fmaf(a1, w0.y, acc0[1].y);
            acc0[1].z = fmaf(a1, w0.z, acc0[1].z); acc0[1].w = fmaf(a1, w0.w, acc0[1].w);
            acc1[1].x = fmaf(a1, w1.x, acc1[1].x); acc1[1].y = fmaf(a1, w1.y, acc1[1].y);
            acc1[1].z = fmaf(a1, w1.z, acc1[1].z); acc1[1].w = fmaf(a1, w1.w, acc1[1].w);
            acc0[2].x = fmaf(a2, w0.x, acc0[2].x); acc0[2].y = fmaf(a2, w0.y, acc0[2].y);
            acc0[2].z = fmaf(a2, w0.z, acc0[2].z); acc0[2].w = fmaf(a2, w0.w, acc0[2].w);
            acc1[2].x = fmaf(a2, w1.x, acc1[2].x); acc1[2].y = fmaf(a2, w1.y, acc1[2].y);
            acc1[2].z = fmaf(a2, w1.z, acc1[2].z); acc1[2].w = fmaf(a2, w1.w, acc1[2].w);
            acc0[3].x = fmaf(a3, w0.x, acc0[3].x); acc0[3].y = fmaf(a3, w0.y, acc0[3].y);
            acc0[3].z = fmaf(a3, w0.z, acc0[3].z); acc0[3].w = fmaf(a3, w0.w, acc0[3].w);
            acc1[3].x = fmaf(a3, w1.x, acc1[3].x); acc1[3].y = fmaf(a3, w1.y, acc1[3].y);
            acc1[3].z = fmaf(a3, w1.z, acc1[3].z); acc1[3].w = fmaf(a3, w1.w, acc1[3].w);
        }
        __syncthreads();
    }
    float4 bA = *(const float4*)(bias + cg * 8);
    float4 bB = *(const float4*)(bias + cg * 8 + 4);
    #pragma unroll
    for (int j = 0; j < 4; ++j) {
        int n = nbase + ng * 4 + j;
        if (n < N) {
            float4 oA = { acc0[j].x + bA.x, acc0[j].y + bA.y, acc0[j].z + bA.z, acc0[j].w + bA.w };
            float4 oB = { acc1[j].x + bB.x, acc1[j].y + bB.y, acc1[j].z + bB.z, acc1[j].w + bB.w };
            *(float4*)(out_node + (size_t)n * C + cg * 8)     = oA;
            *(float4*)(out_node + (size_t)n * C + cg * 8 + 4) = oB;
        }
    }
}

// ============ kT: coalesced out_att (recompute bitwise-identical logit) ====
__global__ __launch_bounds__(256) void kT(const int* __restrict__ src,
        const int* __restrict__ dst, const float* __restrict__ ea,
        const float* __restrict__ dvec, const float* __restrict__ mA,
        const float* __restrict__ invA, float* __restrict__ out_att, int E) {
    int e = blockIdx.x * 256 + threadIdx.x;
    if (e >= E) return;
    float4 a = ((const float4*)ea)[e];
    float mean = (a.x + a.y + a.z + a.w) * 0.25f;
    float r = mean * dvec[src[e]];
    int d = dst[e];
    out_att[e] = expf(r - mA[d]) * invA[d];
}

extern "C" void kernel_launch(void* const* d_in, const int* in_sizes, int n_in,
                              void* d_out, int out_size, void* d_ws, size_t ws_size,
                              hipStream_t stream) {
    const float* x    = (const float*)d_in[0];
    const float* ea   = (const float*)d_in[1];
    const float* W    = (const float*)d_in[2];
    const float* bias = (const float*)d_in[3];
    const float* attv = (const float*)d_in[4];
    const int*   ei   = (const int*)d_in[5];

    int N = in_sizes[0] / C;
    int E = in_sizes[5] / 2;
    const int* src = ei;
    const int* dst = ei + E;

    float* out_node = (float*)d_out;
    float* out_att  = (float*)d_out + (size_t)N * C;

    char* ws = (char*)d_ws;
    float* agg  = (float*)ws; ws += (size_t)N * KCOEF * C * sizeof(float);
    float4* pay = (float4*)ws; ws += (size_t)E * 32;    // 32 B/edge payload
    float* dvec = (float*)ws; ws += (size_t)N * sizeof(float);
    int*   deg  = (int*)ws;   ws += (size_t)N * sizeof(int);
    int*   off  = (int*)ws;   ws += (size_t)N * sizeof(int);
    int*   cur  = (int*)ws;   ws += (size_t)N * sizeof(int);
    int*   bsum = (int*)ws;   ws += 1024;

    // overlays (dead-after-use buffers reused for softmax stats)
    float* mA   = (float*)cur;   // cur dead after kP
    float* invA = (float*)deg;   // deg dead after kE3 reads it

    int NB  = (N + 255) / 256;       // scan blocks (196 <= 256)
    int NBD = (N + 15) / 16;         // dvec blocks
    int NBH = (E + 255) / 256;       // histogram blocks
    int NBF = (N + FN - 1) / FN;     // kF3 node blocks

    hipMemsetAsync(deg, 0, (size_t)N * sizeof(int), stream);
    kAH <<<NBD + NBH, 256, 0, stream>>>(x, attv, dst, dvec, deg, N, E, NBD);
    kS1 <<<NB, 256, 0, stream>>>(deg, off, bsum, N);
    kS2 <<<1, 256, 0, stream>>>(bsum, NB);
    kS3 <<<NB, 256, 0, stream>>>(off, bsum, cur, N);
    kP  <<<(E + 1023) / 1024, 256, 0, stream>>>(src, dst, ea, dvec, cur, pay, E);
    kE3 <<<(N + 3) / 4, 256, 0, stream>>>(x, pay, off, deg, invA, mA, agg, N, E);
    kF3 <<<NBF, 256, 0, stream>>>(agg, x, W, bias, out_node, N);
    kT  <<<(E + 255) / 256, 256, 0, stream>>>(src, dst, ea, dvec, mA, invA, out_att, E);
}